// Round 8
// baseline (891.489 us; speedup 1.0000x reference)
//
#include <hip/hip_runtime.h>
#include <hip/hip_bf16.h>
#include <stdint.h>

#define VOCAB 32000
#define HID   256
#define BATCH 16
#define SEQT  256
#define ROWS  (BATCH*SEQT)   // 4096

typedef __attribute__((ext_vector_type(8))) short bf16x8_t;
typedef __attribute__((ext_vector_type(4))) float f32x4_t;

__device__ __forceinline__ short f2bs(float x) {
    __hip_bfloat16 h = __float2bfloat16(x);
    return *reinterpret_cast<short*>(&h);
}
__device__ __forceinline__ bf16x8_t cvt8(float4 a, float4 b) {
    union { short s[8]; bf16x8_t v; } u;
    u.s[0] = f2bs(a.x); u.s[1] = f2bs(a.y); u.s[2] = f2bs(a.z); u.s[3] = f2bs(a.w);
    u.s[4] = f2bs(b.x); u.s[5] = f2bs(b.y); u.s[6] = f2bs(b.z); u.s[7] = f2bs(b.w);
    return u.v;
}
// workgroup barrier draining ONLY lgkmcnt; vmem stays in flight
__device__ __forceinline__ void barrier_lds() {
    asm volatile("s_waitcnt lgkmcnt(0)\n\ts_barrier" ::: "memory");
}
// tanh via exp2: tanh(x) = 1 - 2/(2^(2*log2(e)*x)+1); saturates naturally.
__device__ __forceinline__ float tanh_exp(float x) {
    float e = __builtin_amdgcn_exp2f(x * 2.885390081777927f);
    return fmaf(-2.f, __builtin_amdgcn_rcpf(e + 1.f), 1.f);
}
// pack two f32 -> one dword of 2 bf16 (RNE), lo = first operand
__device__ __forceinline__ uint32_t pk_bf16(float lo, float hi) {
    uint32_t r;
    asm("v_cvt_pk_bf16_f32 %0, %1, %2" : "=v"(r) : "v"(lo), "v"(hi));
    return r;
}
// async global->LDS, 16B per lane: LDS dest = wave-uniform base + lane*16
__device__ __forceinline__ void gload_lds16(const short* g, short* lds_base) {
    __builtin_amdgcn_global_load_lds(
        (const __attribute__((address_space(1))) void*)g,
        (__attribute__((address_space(3))) void*)lds_base, 16, 0, 0);
}

// ===========================================================================
// Swizzled fragment layout (shared by A=hs and B=Wfcb):
//   element (row, k) -> swz[ (row>>4)*4096 + (k>>5)*512 + ((k>>3)&3)*128
//                            + (row&15)*8 + (k&7) ]
// A fragment (one 16-row tile, one ki) is 1 KB contiguous, lane-linear.
// ===========================================================================

struct RnnS { short hbuf[2][16][264]; };                       // 16.9 KB
struct FcS  { short As[2][8][512]; short Bs[2][16][512]; int tgt[128]; }; // 49.7 KB
union  SMem { RnnS r; FcS f; };

// ---------------------------------------------------------------------------
// K1: xp[t][b][h] = Wih[inputs[b][t]][h]+bih[h]+bhh[h]; zeroes S.
// ---------------------------------------------------------------------------
__global__ __launch_bounds__(256) void xproj_kernel(
    const int* __restrict__ inputs,
    const float* __restrict__ Wih,
    const float* __restrict__ bih,
    const float* __restrict__ bhh,
    float* __restrict__ xp,
    float* __restrict__ S)
{
    int idx = blockIdx.x * 256 + threadIdx.x;  // (t*16+b)*256 + h
    int h  = idx & 255;
    int tb = idx >> 8;
    int b  = tb & 15;
    int t  = tb >> 4;
    int id = inputs[b * SEQT + t];
    xp[idx] = Wih[(size_t)id * HID + h] + bih[h] + bhh[h];
    if (idx < ROWS) S[idx] = 0.0f;
}

// ---------------------------------------------------------------------------
// RNN chunk [t0,t1): R2-exact proven core; 512 thr, 8 waves. State carried
// through hs (swizzled): chunk start reloads h_{t0-1} into LDS; every step
// stores h_{t-1} to hs (coalesced bf16x8 per thread, pipelined).
// ---------------------------------------------------------------------------
__device__ void rnn_chunk(const float* __restrict__ xp,
                          const float* __restrict__ Whh,
                          __hip_bfloat16* __restrict__ hs,
                          int t0, int t1, RnnS& rs)
{
    auto& hbuf = rs.hbuf;
    const int tid = threadIdx.x;
    const int l = tid & 63, w = tid >> 6;
    const int lr = l & 15, lh = l >> 4;
    const int cm = tid >> 5;               // copy: row 0..15
    const int cc = (tid & 31) * 8;         // copy: col (x8 shorts)
    const int n0 = w * 32 + lr * 2;        // this lane's even column
    const int cpoff = ((cc >> 5) * 512) + (((cc >> 3) & 3) * 128) + cm * 8;

    bf16x8_t bfrag[2][8];
#pragma unroll
    for (int nt = 0; nt < 2; nt++)
#pragma unroll
        for (int ki = 0; ki < 8; ki++) {
            const float4* p = (const float4*)(Whh + (size_t)(n0 + nt) * HID + ki * 32 + lh * 8);
            bfrag[nt][ki] = cvt8(p[0], p[1]);
        }
    if (t0 == 0) {
        for (int i = tid; i < 16 * 264; i += 512) ((short*)hbuf[0])[i] = 0;
    } else {
        // inverse of the copy-out mapping: reload h_{t0-1}
        *(bf16x8_t*)(&hbuf[0][cm][cc]) =
            *(const bf16x8_t*)((const short*)hs + (size_t)(t0 - 1) * 4096 + cpoff);
    }
    __syncthreads();

    float2 xva[4], xvb[4];
#pragma unroll
    for (int r = 0; r < 4; r++)
        xva[r] = *(const float2*)(xp + (size_t)t0 * (BATCH * HID) + (lh * 4 + r) * HID + n0);

    auto step = [&](int SRC, int DST, float2* xc, float2* xn, int t) {
        if (t > 0) {
            bf16x8_t hv = *(const bf16x8_t*)(&hbuf[SRC][cm][cc]);
            *(bf16x8_t*)((short*)hs + (size_t)(t - 1) * 4096 + cpoff) = hv;
        }
        bf16x8_t afr[8];
#pragma unroll
        for (int ki = 0; ki < 8; ki++)
            afr[ki] = *(const bf16x8_t*)(&hbuf[SRC][lr][ki * 32 + lh * 8]);

        f32x4_t a0a = {xc[0].x, xc[1].x, xc[2].x, xc[3].x};
        f32x4_t a1a = {xc[0].y, xc[1].y, xc[2].y, xc[3].y};
        f32x4_t a0b = {0.f, 0.f, 0.f, 0.f};
        f32x4_t a1b = {0.f, 0.f, 0.f, 0.f};
#pragma unroll
        for (int ki = 0; ki < 4; ki++) {
            a0a = __builtin_amdgcn_mfma_f32_16x16x32_bf16(afr[ki],     bfrag[0][ki],     a0a, 0, 0, 0);
            a0b = __builtin_amdgcn_mfma_f32_16x16x32_bf16(afr[ki + 4], bfrag[0][ki + 4], a0b, 0, 0, 0);
            a1a = __builtin_amdgcn_mfma_f32_16x16x32_bf16(afr[ki],     bfrag[1][ki],     a1a, 0, 0, 0);
            a1b = __builtin_amdgcn_mfma_f32_16x16x32_bf16(afr[ki + 4], bfrag[1][ki + 4], a1b, 0, 0, 0);
        }

        if (t + 1 < SEQT) {
            const float* xb = xp + (size_t)(t + 1) * (BATCH * HID);
#pragma unroll
            for (int r = 0; r < 4; r++)
                xn[r] = *(const float2*)(xb + (lh * 4 + r) * HID + n0);
        }

#pragma unroll
        for (int r = 0; r < 4; r++) {
            float v0 = a0a[r] + a0b[r];
            float v1 = a1a[r] + a1b[r];
            uint32_t pk = pk_bf16(tanh_exp(v0), tanh_exp(v1));
            *(uint32_t*)(&hbuf[DST][lh * 4 + r][n0]) = pk;
        }
        barrier_lds();
    };

    for (int t = t0; t < t1; t += 2) {
        step(0, 1, xva, xvb, t);
        step(1, 0, xvb, xva, t + 1);
    }
    bf16x8_t hv = *(const bf16x8_t*)(&hbuf[0][cm][cc]);
    *(bf16x8_t*)((short*)hs + (size_t)(t1 - 1) * 4096 + cpoff) = hv;
}

// ---------------------------------------------------------------------------
// FC tile (R5-verified 512-thr body, fence-free): 128m x 256n, K=256 in 8
// slabs; global_load_lds staging, counted vmcnt(3), lgkm-only barriers.
// Wave w stages A tile w + B tiles {2w,2w+1}; computes 64x64 at
// (wm=(w>>2)*64, wn=(w&3)*64). Fused bias+exp+rowsum+target epilogue.
// ---------------------------------------------------------------------------
__device__ void fc_tile(const __hip_bfloat16* __restrict__ hsz,
                        const __hip_bfloat16* __restrict__ Wfcb,
                        const float* __restrict__ bfc,
                        const int* __restrict__ targets,
                        float* __restrict__ S,
                        float* __restrict__ TL,
                        int m_id, int n2, FcS& fs)
{
    const int tid = threadIdx.x;
    const int l = tid & 63, w = tid >> 6;
    const int lr = l & 15, lh = l >> 4;
    const int wm = (w >> 2) * 64, wn = (w & 3) * 64;
    const int m0 = m_id * 128, n0 = n2 * 256;

    // tile preamble: drain prior tile's vmem + lgkm, then barrier
    asm volatile("s_waitcnt vmcnt(0) lgkmcnt(0)\n\ts_barrier" ::: "memory");

    if (tid < 128) {
        int r = m0 + tid;                    // r = t*16+b
        fs.tgt[tid] = targets[((r & 15) << 8) | (r >> 4)];
    }
    __builtin_amdgcn_sched_barrier(0);

    const short* Ag = (const short*)hsz  + (size_t)(m_id * 8 + w)   * 4096 + l * 8;
    const short* Bg = (const short*)Wfcb + (size_t)(n2 * 16 + 2*w)  * 4096 + l * 8;

    f32x4_t acc[4][4];
    const f32x4_t z = {0.f, 0.f, 0.f, 0.f};
#pragma unroll
    for (int i = 0; i < 4; i++)
#pragma unroll
        for (int jj = 0; jj < 4; jj++) acc[i][jj] = z;

    auto stage = [&](int buf, int s) {       // 3 wave-instrs, zero VALU
        gload_lds16(Ag + s * 512,        &fs.As[buf][w][0]);
        gload_lds16(Bg + s * 512,        &fs.Bs[buf][2 * w][0]);
        gload_lds16(Bg + 4096 + s * 512, &fs.Bs[buf][2 * w + 1][0]);
    };
    stage(0, 0);
    stage(1, 1);
    __builtin_amdgcn_sched_barrier(0);

#pragma unroll
    for (int s = 0; s < 8; s++) {
        const int buf = s & 1;
        if (s < 7) asm volatile("s_waitcnt vmcnt(3)\n\ts_barrier" ::: "memory");
        else       asm volatile("s_waitcnt vmcnt(0)\n\ts_barrier" ::: "memory");

        bf16x8_t a[4], b[4];
#pragma unroll
        for (int mt = 0; mt < 4; mt++)
            a[mt] = *(const bf16x8_t*)&fs.As[buf][(w >> 2) * 4 + mt][l * 8];
#pragma unroll
        for (int nt = 0; nt < 4; nt++)
            b[nt] = *(const bf16x8_t*)&fs.Bs[buf][(w & 3) * 4 + nt][l * 8];

        if (s < 6) {
            barrier_lds();                   // all waves done reading buf
            stage(buf, s + 2);               // refill 2 slabs ahead
            __builtin_amdgcn_sched_barrier(0);
        }
#pragma unroll
        for (int mt = 0; mt < 4; mt++)
#pragma unroll
            for (int nt = 0; nt < 4; nt++)
                acc[mt][nt] = __builtin_amdgcn_mfma_f32_16x16x32_bf16(
                    a[mt], b[nt], acc[mt][nt], 0, 0, 0);
    }

    // epilogue: bias + exp + rowsum; extract target logits inline
    int tg[16];
#pragma unroll
    for (int i = 0; i < 16; i++)
        tg[i] = fs.tgt[wm + (i >> 2) * 16 + lh * 4 + (i & 3)];

    float rsum[16];
#pragma unroll
    for (int i = 0; i < 16; i++) rsum[i] = 0.f;
#pragma unroll
    for (int nt = 0; nt < 4; nt++) {
        int n = n0 + wn + nt * 16 + lr;
        float bias = bfc[n];
#pragma unroll
        for (int mt = 0; mt < 4; mt++)
#pragma unroll
            for (int r = 0; r < 4; r++) {
                float v = acc[mt][nt][r] + bias;
                rsum[mt * 4 + r] += __expf(v);
                if (tg[mt * 4 + r] == n)
                    TL[m0 + wm + mt * 16 + lh * 4 + r] = v;
            }
    }
#pragma unroll
    for (int m = 1; m < 16; m <<= 1)
#pragma unroll
        for (int i = 0; i < 16; i++) rsum[i] += __shfl_xor(rsum[i], m, 64);
    if (lr == 0) {
#pragma unroll
        for (int i = 0; i < 16; i++) {
            int r = m0 + wm + (i >> 2) * 16 + lh * 4 + (i & 3);
            atomicAdd(&S[r], rsum[i]);
        }
    }
}

// ---------------------------------------------------------------------------
// Fused chunk kernel.
//  rnn_t0 >= 0  : block 0 runs rnn steps [rnn_t0, rnn_t1)
//  do_cvt       : other blocks convert Wfc -> swizzled bf16 Wfcb
//  fc_mbase >= 0: other blocks grid-stride fc tiles m in [fc_mbase,fc_mbase+8)
// Coherence: fc reads only hs written by PREVIOUS launches (kernel-boundary
// flush, same mechanism as R1-R7); within a launch rnn/fc address ranges are
// disjoint. No fences (R5 lesson: agent-acquire = L2 nuke).
// ---------------------------------------------------------------------------
__global__ __launch_bounds__(512, 1) void fused_kernel(
    const float* __restrict__ xp,
    const float* __restrict__ Whh,
    __hip_bfloat16* __restrict__ hs,
    const float* __restrict__ Wfc,
    __hip_bfloat16* __restrict__ Wfcb,
    const float* __restrict__ bfc,
    const int* __restrict__ targets,
    float* __restrict__ S,
    float* __restrict__ TL,
    int rnn_t0, int rnn_t1, int fc_mbase, int do_cvt)
{
    __shared__ SMem sm;
    const int has_rnn = (rnn_t0 >= 0) ? 1 : 0;
    if (has_rnn && blockIdx.x == 0) {
        rnn_chunk(xp, Whh, hs, rnn_t0, rnn_t1, sm.r);
        return;
    }
    const int g   = (int)blockIdx.x - has_rnn;
    const int nfc = (int)gridDim.x - has_rnn;
    if (do_cvt) {
        for (int idx = g * 512 + (int)threadIdx.x; idx < (VOCAB * HID / 8); idx += nfc * 512) {
            int e   = idx * 8;
            int m   = (e >> 3) & 15;
            int lhh = (e >> 7) & 3;
            int ki  = (e >> 9) & 7;
            int tile = e >> 12;
            const float4* p = (const float4*)(Wfc + (size_t)(tile * 16 + m) * HID
                                              + ki * 32 + lhh * 8);
            *(bf16x8_t*)((short*)Wfcb + (size_t)e) = cvt8(p[0], p[1]);
        }
        return;
    }
    if (fc_mbase >= 0) {
        for (int tt = g; tt < 8 * 125; tt += nfc)
            fc_tile(hs, Wfcb, bfc, targets, S, TL, fc_mbase + tt / 125, tt % 125, sm.f);
    }
}

// ---------------------------------------------------------------------------
// Fallback FC (tiny workspace): fp32 B, register staging, atomic S.
// ---------------------------------------------------------------------------
__global__ __launch_bounds__(256) void fc_fb_kernel(
    const __hip_bfloat16* __restrict__ hsz,
    const float* __restrict__ Bf,
    const float* __restrict__ bfc,
    const int* __restrict__ targets,
    float* __restrict__ S,
    float* __restrict__ TL)
{
    __shared__ __align__(16) short As[8 * 512];
    __shared__ __align__(16) short Bs[8 * 512];
    __shared__ int tgt[128];

    const int bid = blockIdx.x;
    const int xcd = bid & 7;
    const int j   = bid >> 3;
    const int m_id = j & 31;
    const int n_id = (j >> 5) * 8 + xcd;
    if (n_id >= VOCAB / 128) return;
    const int m0 = m_id * 128, n0 = n_id * 128;

    const int tid = threadIdx.x;
    const int l = tid & 63, w = tid >> 6;
    const int lr = l & 15, lh = l >> 4;
    const int wm = (w >> 1) * 64, wn = (w & 1) * 64;

    if (tid < 128) {
        int r = m0 + tid;
        tgt[tid] = targets[((r & 15) << 8) | (r >> 4)];
    }
    const short* Ag = (const short*)hsz + (size_t)m_id * 32768 + (size_t)(w * 2) * 4096 + l * 8;

    f32x4_t acc[4][4];
    const f32x4_t z = {0.f, 0.f, 0.f, 0.f};
#pragma unroll
    for (int i = 0; i < 4; i++)
#pragma unroll
        for (int jj = 0; jj < 4; jj++) acc[i][jj] = z;

    for (int s = 0; s < 8; s++) {
        __syncthreads();
#pragma unroll
        for (int i = 0; i < 2; i++) {
            int tt = w * 2 + i;
            bf16x8_t va = *(const bf16x8_t*)(Ag + i * 4096 + s * 512);
            *(bf16x8_t*)&As[tt * 512 + l * 8] = va;
            int n = n0 + tt * 16 + lr;
            const float4* p = (const float4*)(Bf + (size_t)n * HID + s * 32 + lh * 8);
            *(bf16x8_t*)&Bs[tt * 512 + l * 8] = cvt8(p[0], p[1]);
        }
        __syncthreads();
        bf16x8_t a[4], b[4];
#pragma unroll
        for (int mt = 0; mt < 4; mt++)
            a[mt] = *(const bf16x8_t*)&As[(((w >> 1) * 4 + mt) * 512) + l * 8];
#pragma unroll
        for (int nt = 0; nt < 4; nt++)
            b[nt] = *(const bf16x8_t*)&Bs[(((w & 1) * 4 + nt) * 512) + l * 8];
#pragma unroll
        for (int mt = 0; mt < 4; mt++)
#pragma unroll
            for (int nt = 0; nt < 4; nt++)
                acc[mt][nt] = __builtin_amdgcn_mfma_f32_16x16x32_bf16(
                    a[mt], b[nt], acc[mt][nt], 0, 0, 0);
    }

    int tg[16];
#pragma unroll
    for (int i = 0; i < 16; i++)
        tg[i] = tgt[wm + (i >> 2) * 16 + lh * 4 + (i & 3)];
    float rsum[16];
#pragma unroll
    for (int i = 0; i < 16; i++) rsum[i] = 0.f;
#pragma unroll
    for (int nt = 0; nt < 4; nt++) {
        int n = n0 + wn + nt * 16 + lr;
        float bias = bfc[n];
#pragma unroll
        for (int mt = 0; mt < 4; mt++)
#pragma unroll
            for (int r = 0; r < 4; r++) {
                float v = acc[mt][nt][r] + bias;
                rsum[mt * 4 + r] += __expf(v);
                if (tg[mt * 4 + r] == n)
                    TL[m0 + wm + mt * 16 + lh * 4 + r] = v;
            }
    }
#pragma unroll
    for (int m = 1; m < 16; m <<= 1)
#pragma unroll
        for (int i = 0; i < 16; i++) rsum[i] += __shfl_xor(rsum[i], m, 64);
    if (lr == 0) {
#pragma unroll
        for (int i = 0; i < 16; i++) {
            int r = m0 + wm + (i >> 2) * 16 + lh * 4 + (i & 3);
            atomicAdd(&S[r], rsum[i]);
        }
    }
}

// ---------------------------------------------------------------------------
// K4: loss = mean_r( log(S[r]) - TL[r] )
// ---------------------------------------------------------------------------
__global__ __launch_bounds__(256) void loss_kernel(
    const float* __restrict__ S,
    const float* __restrict__ TL,
    float* __restrict__ out)
{
    int tid = threadIdx.x;
    float p = 0.f;
    for (int i = tid; i < ROWS; i += 256) p += __logf(S[i]) - TL[i];
#pragma unroll
    for (int m = 1; m < 64; m <<= 1) p += __shfl_xor(p, m, 64);
    __shared__ float red[4];
    if ((tid & 63) == 0) red[tid >> 6] = p;
    __syncthreads();
    if (tid == 0)
        out[0] = (red[0] + red[1] + red[2] + red[3]) / (float)ROWS;
}

extern "C" void kernel_launch(void* const* d_in, const int* in_sizes, int n_in,
                              void* d_out, int out_size, void* d_ws, size_t ws_size,
                              hipStream_t stream)
{
    (void)in_sizes; (void)n_in; (void)out_size;
    const int*   inputs  = (const int*)d_in[0];
    const int*   targets = (const int*)d_in[1];
    const float* Wih = (const float*)d_in[2];
    const float* bih = (const float*)d_in[3];
    const float* Whh = (const float*)d_in[4];
    const float* bhh = (const float*)d_in[5];
    const float* Wfc = (const float*)d_in[6];
    const float* bfc = (const float*)d_in[7];

    float* S  = (float*)d_ws;                           // 4096 f32
    float* TL = S + ROWS;                               // 4096 f32
    float* xp = TL + ROWS;                              // [T][B][H] fp32, 4 MB
    __hip_bfloat16* hs = (__hip_bfloat16*)(xp + (size_t)SEQT * BATCH * HID); // 2 MB swizzled
    __hip_bfloat16* Wfcb = hs + (size_t)ROWS * HID;     // 16 MB swizzled

    const size_t need = (size_t)(2 * ROWS) * 4 + (size_t)ROWS * HID * 4
                      + (size_t)ROWS * HID * 2 + (size_t)VOCAB * HID * 2;
    const int use_bf16b = (ws_size >= need) ? 1 : 0;

    xproj_kernel<<<(SEQT * BATCH * HID) / 256, 256, 0, stream>>>(
        inputs, Wih, bih, bhh, xp, S);

    if (use_bf16b) {
        // chunk 0: rnn t[0,64) || Wfcb conversion on 256 blocks
        fused_kernel<<<257, 512, 0, stream>>>(xp, Whh, hs, Wfc, Wfcb, bfc, targets,
                                              S, TL, 0, 64, -1, 1);
        // chunks 1..3: rnn t[64c,64c+64) || fc for m produced by chunk c-1
        for (int c = 1; c < 4; c++)
            fused_kernel<<<769, 512, 0, stream>>>(xp, Whh, hs, Wfc, Wfcb, bfc, targets,
                                                  S, TL, 64 * c, 64 * c + 64, 8 * (c - 1), 0);
        // tail: fc for m in [24,32)
        fused_kernel<<<768, 512, 0, stream>>>(xp, Whh, hs, Wfc, Wfcb, bfc, targets,
                                              S, TL, -1, -1, 24, 0);
    } else {
        fused_kernel<<<1, 512, 0, stream>>>(xp, Whh, hs, Wfc, Wfcb, bfc, targets,
                                            S, TL, 0, SEQT, -1, 0);
        fc_fb_kernel<<<8192, 256, 0, stream>>>(hs, Wfc, bfc, targets, S, TL);
    }
    loss_kernel<<<1, 256, 0, stream>>>(S, TL, (float*)d_out);
}